// Round 7
// baseline (69.324 us; speedup 1.0000x reference)
//
#include <hip/hip_runtime.h>
#include <hip/hip_fp16.h>
#include <math.h>

#define POOLSZ 7
#define GRIDG 8          // POOLSZ + 1
#define CCH  256         // channels (fixed by reference setup)
#define NBIN 256         // 4 levels x 8x8 spatial tiles
#define OPP  (POOLSZ * POOLSZ)   // 49
#define SPADH 51         // LDS ushort stride for staged output
#define MAXPER 8         // max RoIs per thread in fused sort (R <= 2048)

typedef float  fx4 __attribute__((ext_vector_type(4)));   // native vec for nontemporal

// ---- exact level computation (must match numpy bit-for-bit) ----
__device__ __forceinline__ int roi_level(const float* __restrict__ rois, int r) {
    const float x1 = rois[r * 5 + 1];
    const float y1 = rois[r * 5 + 2];
    const float x2 = rois[r * 5 + 3];
    const float y2 = rois[r * 5 + 4];
    const float h = __fadd_rn(__fsub_rn(y2, y1), 1.0f);
    const float w = __fadd_rn(__fsub_rn(x2, x1), 1.0f);
    const float s = __fsqrt_rn(__fmul_rn(h, w));
    const float LOG2 = __uint_as_float(0x3F317218u);   // np.float32(np.log(2.0))
    float lv = floorf(__fadd_rn(__fdiv_rn(logf(__fdiv_rn(s, 224.0f)), LOG2), 4.0f));
    lv = fminf(fmaxf(lv, 2.0f), 5.0f);
    return (int)lv;
}

// ---- fused transpose (all levels) + sort (last block) ----
__global__ __launch_bounds__(256) void prep_kernel(
    const float* __restrict__ p2, const float* __restrict__ p3,
    const float* __restrict__ p4, const float* __restrict__ p5,
    __half* __restrict__ t2, __half* __restrict__ t3,
    __half* __restrict__ t4, __half* __restrict__ t5,
    int HW2, int HW3, int HW4, int HW5,
    const float* __restrict__ rois, const float* __restrict__ im_info,
    int R, int* __restrict__ sorted, int nblkT)
{
    const int t = threadIdx.x;

    if ((int)blockIdx.x == nblkT) {
        // ---------------- sort block ----------------
        __shared__ int cnt[NBIN];
        __shared__ int tmp[NBIN];
        cnt[t] = 0;
        __syncthreads();

        int myR[MAXPER], myBin[MAXPER], mySlot[MAXPER];
        int m = 0;
        const float ih = im_info[0], iw = im_info[1];
        for (int r = t; r < R && m < MAXPER; r += 256) {
            const int lvl = roi_level(rois, r);
            const float cx = 0.5f * (rois[r * 5 + 1] + rois[r * 5 + 3]);
            const float cy = 0.5f * (rois[r * 5 + 2] + rois[r * 5 + 4]);
            const int tx = min(7, max(0, (int)(cx * 8.0f / iw)));
            const int ty = min(7, max(0, (int)(cy * 8.0f / ih)));
            const int bin = (lvl - 2) * 64 + ty * 8 + tx;
            myR[m] = r; myBin[m] = bin;
            mySlot[m] = atomicAdd(&cnt[bin], 1);
            ++m;
        }
        __syncthreads();

        const int v = cnt[t];
        tmp[t] = v;
        __syncthreads();
        for (int s = 1; s < NBIN; s <<= 1) {
            const int u = (t >= s) ? tmp[t - s] : 0;
            __syncthreads();
            tmp[t] += u;
            __syncthreads();
        }
        cnt[t] = tmp[t] - v;   // exclusive offsets
        __syncthreads();

        for (int i = 0; i < m; ++i)
            sorted[cnt[myBin[i]] + mySlot[i]] = myR[i];
        return;
    }

    // ---------------- transpose blocks ----------------
    const int n2 = (HW2 / 64) * 4, n3 = (HW3 / 64) * 4, n4 = (HW4 / 64) * 4;
    int bid = blockIdx.x;
    const float* src; __half* dst; int HW;
    if (bid < n2)              { src = p2; dst = t2; HW = HW2; }
    else if ((bid -= n2) < n3) { src = p3; dst = t3; HW = HW3; }
    else if ((bid -= n3) < n4) { src = p4; dst = t4; HW = HW4; }
    else { bid -= n4;            src = p5; dst = t5; HW = HW5; }
    const int ptiles = HW / 64;
    const int pt = bid % ptiles, ct = bid / ptiles;
    const int pbase = pt * 64, cbase = ct * 64;

    __shared__ float tile[64][65];

    // read: 4 passes of 16 channels, nontemporal 16B per lane (coalesced)
    const int l = t & 15, cr = t >> 4;
#pragma unroll
    for (int p = 0; p < 4; ++p) {
        const int c = p * 16 + cr;
        const fx4* sp = (const fx4*)(src + (size_t)(cbase + c) * HW + pbase + l * 4);
        const fx4 v = __builtin_nontemporal_load(sp);
        tile[c][l * 4 + 0] = v.x;
        tile[c][l * 4 + 1] = v.y;
        tile[c][l * 4 + 2] = v.z;
        tile[c][l * 4 + 3] = v.w;
    }
    __syncthreads();

    // write: 8 passes of 8 pixel-rows, half2 per lane (coalesced, cached)
    const int ch2 = t & 31, pr = t >> 5;
#pragma unroll
    for (int p = 0; p < 8; ++p) {
        const int row = p * 8 + pr;
        const __half2 h = __floats2half2_rn(tile[ch2 * 2][row], tile[ch2 * 2 + 1][row]);
        *(__half2*)(dst + (size_t)(pbase + row) * CCH + cbase + ch2 * 2) = h;
    }
}

// ---- main kernel (transposed fp16 layout): block per RoI, lane = channel ----
__global__ __launch_bounds__(256) void fpn_main_t(
    const __half* __restrict__ t2, const __half* __restrict__ t3,
    const __half* __restrict__ t4, const __half* __restrict__ t5,
    const float* __restrict__ rois, const float* __restrict__ im_info,
    float* __restrict__ out, const int* __restrict__ order,
    int H2, int H3, int H4, int H5, int R)
{
    // bijective XCD chunk swizzle
    const int n = blockIdx.x;
    const int q = R / 8, rem = R % 8;
    const int xcd = n % 8, idx = n / 8;
    const int nsw = (xcd < rem ? xcd * (q + 1) : rem * (q + 1) + (xcd - rem) * q) + idx;
    const int r = order ? order[nsw] : nsw;
    const int t = threadIdx.x;   // channel

    const float x1 = rois[r * 5 + 1];
    const float y1 = rois[r * 5 + 2];
    const float x2 = rois[r * 5 + 3];
    const float y2 = rois[r * 5 + 4];

    const int lvl = roi_level(rois, r);
    const __half* feat;
    int H;
    switch (lvl) {
        case 2:  feat = t2; H = H2; break;
        case 3:  feat = t3; H = H3; break;
        case 4:  feat = t4; H = H4; break;
        default: feat = t5; H = H5; break;
    }
    const int W = H;

    // grid coords (exact numpy arithmetic on the index path)
    const float im_h  = im_info[0];
    const float scale = __fdiv_rn((float)H, im_h);
    const float ylo = __fmul_rn(y1, scale), yhi = __fmul_rn(y2, scale);
    const float xlo = __fmul_rn(x1, scale), xhi = __fmul_rn(x2, scale);

    float wy[GRIDG], wx[GRIDG];
    int yoff[GRIDG], dy[GRIDG], xoff[GRIDG], dx[GRIDG];
#pragma unroll
    for (int i = 0; i < GRIDG; ++i) {
        const float tf = __fdiv_rn((float)i, (float)(GRIDG - 1));
        float ty = __fadd_rn(ylo, __fmul_rn(__fsub_rn(yhi, ylo), tf));
        ty = fminf(fmaxf(ty, 0.0f), (float)(H - 1));
        const float y0f = floorf(ty);
        const int   y0  = (int)y0f;
        yoff[i] = y0 * W * CCH;
        dy[i]   = (min(y0 + 1, H - 1) - y0) * W * CCH;
        wy[i]   = __fsub_rn(ty, y0f);

        float tx = __fadd_rn(xlo, __fmul_rn(__fsub_rn(xhi, xlo), tf));
        tx = fminf(fmaxf(tx, 0.0f), (float)(W - 1));
        const float x0f = floorf(tx);
        const int   x0  = (int)x0f;
        xoff[i] = x0 * CCH;
        dx[i]   = (min(x0 + 1, W - 1) - x0) * CCH;
        wx[i]   = __fsub_rn(tx, x0f);
    }

    __shared__ unsigned short s_out[CCH * SPADH];   // fp16-staged output, 25.5 KB

    float rowPrev[GRIDG], rowCur[GRIDG];
#pragma unroll
    for (int gy = 0; gy < GRIDG; ++gy) {
        const __half* base = feat + yoff[gy] + t;
        const int dyg = dy[gy];
        const float wyg = wy[gy];
        const float omy = 1.0f - wyg;
#pragma unroll
        for (int gx = 0; gx < GRIDG; ++gx) {
            const __half* qp = base + xoff[gx];
            const int dxg = dx[gx];
            const float v00 = __half2float(qp[0]);
            const float v01 = __half2float(qp[dxg]);
            const float v10 = __half2float(qp[dyg]);
            const float v11 = __half2float(qp[dyg + dxg]);
            const float wxg = wx[gx];
            const float omx = 1.0f - wxg;
            rowCur[gx] = omy * (omx * v00 + wxg * v01) + wyg * (omx * v10 + wxg * v11);
        }
        if (gy > 0) {
            const int py = gy - 1;
#pragma unroll
            for (int px = 0; px < POOLSZ; ++px) {
                const float pv = 0.25f * (rowPrev[px] + rowPrev[px + 1]
                                          + rowCur[px] + rowCur[px + 1]);
                s_out[t * SPADH + py * POOLSZ + px] =
                    __half_as_ushort(__float2half_rn(pv));
            }
        }
#pragma unroll
        for (int gx = 0; gx < GRIDG; ++gx) rowPrev[gx] = rowCur[gx];
    }

    __syncthreads();
    // coalesced 16B nontemporal drain: 3136 vec4s = 12 full passes + 64 tail
    float* obase = out + (size_t)r * (CCH * OPP);
    auto rd = [&](unsigned k) -> float {
        const unsigned c = (k * 21400u) >> 20;        // k/49, exact for k<12544
        const unsigned pp = k - c * 49u;
        return __half2float(__ushort_as_half(s_out[c * SPADH + pp]));
    };
#pragma unroll
    for (int i = 0; i < 12; ++i) {
        const unsigned k4 = (unsigned)(i * 256 + t) * 4u;
        fx4 v;
        v.x = rd(k4 + 0); v.y = rd(k4 + 1); v.z = rd(k4 + 2); v.w = rd(k4 + 3);
        __builtin_nontemporal_store(v, (fx4*)(obase + k4));
    }
    if (t < 64) {
        const unsigned k4 = (unsigned)(12 * 256 + t) * 4u;
        fx4 v;
        v.x = rd(k4 + 0); v.y = rd(k4 + 1); v.z = rd(k4 + 2); v.w = rd(k4 + 3);
        __builtin_nontemporal_store(v, (fx4*)(obase + k4));
    }
}

// ---- fallback (round-3 kernel): only if d_ws can't hold the fp16 copies ----
__global__ __launch_bounds__(256) void fpn_roialign_kernel(
    const float* __restrict__ p2, const float* __restrict__ p3,
    const float* __restrict__ p4, const float* __restrict__ p5,
    const float* __restrict__ rois, const float* __restrict__ im_info,
    float* __restrict__ out, const int* __restrict__ order,
    int H2, int H3, int H4, int H5, int R)
{
    const int n = blockIdx.x;
    const int q = R / 8, rem = R % 8;
    const int xcd = n % 8, idx = n / 8;
    const int nsw = (xcd < rem ? xcd * (q + 1) : rem * (q + 1) + (xcd - rem) * q) + idx;
    const int r = order ? order[nsw] : nsw;

    const float bf = rois[r * 5 + 0];
    const float x1 = rois[r * 5 + 1];
    const float y1 = rois[r * 5 + 2];
    const float x2 = rois[r * 5 + 3];
    const float y2 = rois[r * 5 + 4];

    const int lvl = roi_level(rois, r);
    const float* feat;
    int H;
    switch (lvl) {
        case 2:  feat = p2; H = H2; break;
        case 3:  feat = p3; H = H3; break;
        case 4:  feat = p4; H = H4; break;
        default: feat = p5; H = H5; break;
    }
    const int W = H;
    const int wv  = threadIdx.x >> 6;
    const int lid = threadIdx.x & 63;
    const int gy  = lid >> 3;
    const int gx  = lid & 7;

    const float im_h  = im_info[0];
    const float scale = __fdiv_rn((float)H, im_h);
    const float ylo = __fmul_rn(y1, scale), yhi = __fmul_rn(y2, scale);
    const float xlo = __fmul_rn(x1, scale), xhi = __fmul_rn(x2, scale);
    float ty = __fadd_rn(ylo, __fmul_rn(__fsub_rn(yhi, ylo),
                                        __fdiv_rn((float)gy, (float)(GRIDG - 1))));
    ty = fminf(fmaxf(ty, 0.0f), (float)(H - 1));
    float tx = __fadd_rn(xlo, __fmul_rn(__fsub_rn(xhi, xlo),
                                        __fdiv_rn((float)gx, (float)(GRIDG - 1))));
    tx = fminf(fmaxf(tx, 0.0f), (float)(W - 1));
    const float y0f = floorf(ty), x0f = floorf(tx);
    const int   y0  = (int)y0f,   x0  = (int)x0f;
    const int   y1i = min(y0 + 1, H - 1);
    const int   x1i = min(x0 + 1, W - 1);
    const float wyv = __fsub_rn(ty, y0f);
    const float wxv = __fsub_rn(tx, x0f);
    const float omy = 1.0f - wyv;
    const float omx = 1.0f - wxv;

    const int b = (int)bf;
    const size_t plane = (size_t)H * W;
    const float* fbase = feat + (size_t)(b * CCH + wv * 64) * plane;
    const int o00 = y0  * W + x0;
    const int o01 = y0  * W + x1i;
    const int o10 = y1i * W + x0;
    const int o11 = y1i * W + x1i;

    float* obase = out + (size_t)r * (CCH * OPP) + (size_t)(wv * 64) * OPP;
    const bool wr  = (gy < POOLSZ) && (gx < POOLSZ);
    const int oidx = gy * POOLSZ + gx;

#pragma unroll 4
    for (int k = 0; k < 64; ++k) {
        const float* f = fbase + (size_t)k * plane;
        const float v00 = f[o00];
        const float v01 = f[o01];
        const float v10 = f[o10];
        const float v11 = f[o11];
        const float v = omy * (omx * v00 + wxv * v01) + wyv * (omx * v10 + wxv * v11);
        const float vb  = __shfl_down(v, 8);
        const float vr  = __shfl_down(v, 1);
        const float vbr = __shfl_down(v, 9);
        if (wr) obase[k * OPP + oidx] = 0.25f * (((v + vb) + vr) + vbr);
    }
}

extern "C" void kernel_launch(void* const* d_in, const int* in_sizes, int n_in,
                              void* d_out, int out_size, void* d_ws, size_t ws_size,
                              hipStream_t stream) {
    const float* p2      = (const float*)d_in[0];
    const float* p3      = (const float*)d_in[1];
    const float* p4      = (const float*)d_in[2];
    const float* p5      = (const float*)d_in[3];
    const float* rois    = (const float*)d_in[4];
    const float* im_info = (const float*)d_in[5];
    float* out = (float*)d_out;

    const int R = in_sizes[4] / 5;
    auto dimOf = [](int sz) {
        int hw = sz / CCH;
        return (int)(sqrtf((float)hw) + 0.5f);
    };
    const int H2 = dimOf(in_sizes[0]);
    const int H3 = dimOf(in_sizes[1]);
    const int H4 = dimOf(in_sizes[2]);
    const int H5 = dimOf(in_sizes[3]);
    const size_t HW2 = (size_t)H2 * H2, HW3 = (size_t)H3 * H3;
    const size_t HW4 = (size_t)H4 * H4, HW5 = (size_t)H5 * H5;

    // ws layout: sorted[R] ints | t2 | t3 | t4 | t5 (fp16, 256-byte aligned)
    const size_t sortBytes = (size_t)R * sizeof(int);
    const size_t sortPad   = (sortBytes + 255) & ~(size_t)255;
    const size_t transBytes = (HW2 + HW3 + HW4 + HW5) * CCH * sizeof(__half);
    const bool canSort  = (ws_size >= sortBytes) && (R <= 256 * MAXPER);
    const bool canTrans = ws_size >= sortPad + transBytes;

    if (canTrans) {
        int* sorted = canSort ? (int*)d_ws : nullptr;
        __half* t2 = (__half*)((char*)d_ws + sortPad);
        __half* t3 = t2 + HW2 * CCH;
        __half* t4 = t3 + HW3 * CCH;
        __half* t5 = t4 + HW4 * CCH;
        const int nblkT = (int)((HW2 + HW3 + HW4 + HW5) / 64 * 4);
        const int nblk  = nblkT + (canSort ? 1 : 0);
        prep_kernel<<<nblk, 256, 0, stream>>>(
            p2, p3, p4, p5, t2, t3, t4, t5,
            (int)HW2, (int)HW3, (int)HW4, (int)HW5,
            rois, im_info, R, sorted, nblkT);
        fpn_main_t<<<R, 256, 0, stream>>>(
            t2, t3, t4, t5, rois, im_info, out, sorted, H2, H3, H4, H5, R);
    } else {
        fpn_roialign_kernel<<<R, 256, 0, stream>>>(
            p2, p3, p4, p5, rois, im_info, out, nullptr, H2, H3, H4, H5, R);
    }
}

// Round 8
// 63.629 us; speedup vs baseline: 1.0895x; 1.0895x over previous
//
#include <hip/hip_runtime.h>
#include <hip/hip_fp16.h>
#include <math.h>

#define POOLSZ 7
#define GRIDG 8          // POOLSZ + 1
#define CCH  256         // channels (fixed by reference setup)
#define NBIN 256         // 8x8 spatial tiles x 4 levels (spatial-major)
#define OPP  (POOLSZ * POOLSZ)   // 49
#define MAXPER 8         // max RoIs per thread in fused sort (R <= 2048)

typedef float  fx4 __attribute__((ext_vector_type(4)));   // native vec for nontemporal

// ---- exact level computation (must match numpy bit-for-bit) ----
__device__ __forceinline__ int roi_level(const float* __restrict__ rois, int r) {
    const float x1 = rois[r * 5 + 1];
    const float y1 = rois[r * 5 + 2];
    const float x2 = rois[r * 5 + 3];
    const float y2 = rois[r * 5 + 4];
    const float h = __fadd_rn(__fsub_rn(y2, y1), 1.0f);
    const float w = __fadd_rn(__fsub_rn(x2, x1), 1.0f);
    const float s = __fsqrt_rn(__fmul_rn(h, w));
    const float LOG2 = __uint_as_float(0x3F317218u);   // np.float32(np.log(2.0))
    float lv = floorf(__fadd_rn(__fdiv_rn(logf(__fdiv_rn(s, 224.0f)), LOG2), 4.0f));
    lv = fminf(fmaxf(lv, 2.0f), 5.0f);
    return (int)lv;
}

// ---- fused transpose (all levels) + sort (last block) ----
__global__ __launch_bounds__(256) void prep_kernel(
    const float* __restrict__ p2, const float* __restrict__ p3,
    const float* __restrict__ p4, const float* __restrict__ p5,
    __half* __restrict__ t2, __half* __restrict__ t3,
    __half* __restrict__ t4, __half* __restrict__ t5,
    int HW2, int HW3, int HW4, int HW5,
    const float* __restrict__ rois, const float* __restrict__ im_info,
    int R, int* __restrict__ sorted, int nblkT)
{
    const int t = threadIdx.x;

    if ((int)blockIdx.x == nblkT) {
        // ---------------- sort block ----------------
        __shared__ int cnt[NBIN];
        __shared__ int tmp[NBIN];
        cnt[t] = 0;
        __syncthreads();

        int myR[MAXPER], myBin[MAXPER], mySlot[MAXPER];
        int m = 0;
        const float ih = im_info[0], iw = im_info[1];
        for (int r = t; r < R && m < MAXPER; r += 256) {
            const int lvl = roi_level(rois, r);
            const float cx = 0.5f * (rois[r * 5 + 1] + rois[r * 5 + 3]);
            const float cy = 0.5f * (rois[r * 5 + 2] + rois[r * 5 + 4]);
            const int tx = min(7, max(0, (int)(cx * 8.0f / iw)));
            const int ty = min(7, max(0, (int)(cy * 8.0f / ih)));
            // spatial-major, level-minor: balances levels across XCD chunks
            const int bin = (ty * 8 + tx) * 4 + (lvl - 2);
            myR[m] = r; myBin[m] = bin;
            mySlot[m] = atomicAdd(&cnt[bin], 1);
            ++m;
        }
        __syncthreads();

        const int v = cnt[t];
        tmp[t] = v;
        __syncthreads();
        for (int s = 1; s < NBIN; s <<= 1) {
            const int u = (t >= s) ? tmp[t - s] : 0;
            __syncthreads();
            tmp[t] += u;
            __syncthreads();
        }
        cnt[t] = tmp[t] - v;   // exclusive offsets
        __syncthreads();

        for (int i = 0; i < m; ++i)
            sorted[cnt[myBin[i]] + mySlot[i]] = myR[i];
        return;
    }

    // ---------------- transpose blocks ----------------
    const int n2 = (HW2 / 64) * 4, n3 = (HW3 / 64) * 4, n4 = (HW4 / 64) * 4;
    int bid = blockIdx.x;
    const float* src; __half* dst; int HW;
    if (bid < n2)              { src = p2; dst = t2; HW = HW2; }
    else if ((bid -= n2) < n3) { src = p3; dst = t3; HW = HW3; }
    else if ((bid -= n3) < n4) { src = p4; dst = t4; HW = HW4; }
    else { bid -= n4;            src = p5; dst = t5; HW = HW5; }
    const int ptiles = HW / 64;
    const int pt = bid % ptiles, ct = bid / ptiles;
    const int pbase = pt * 64, cbase = ct * 64;

    __shared__ float tile[64][65];

    // read: 4 passes of 16 channels, nontemporal 16B per lane (coalesced;
    // nt keeps p* out of L2 so the fp16 t* stays resident for the main kernel)
    const int l = t & 15, cr = t >> 4;
#pragma unroll
    for (int p = 0; p < 4; ++p) {
        const int c = p * 16 + cr;
        const fx4* sp = (const fx4*)(src + (size_t)(cbase + c) * HW + pbase + l * 4);
        const fx4 v = __builtin_nontemporal_load(sp);
        tile[c][l * 4 + 0] = v.x;
        tile[c][l * 4 + 1] = v.y;
        tile[c][l * 4 + 2] = v.z;
        tile[c][l * 4 + 3] = v.w;
    }
    __syncthreads();

    // write: 8 passes of 8 pixel-rows, half2 per lane (coalesced, cached)
    const int ch2 = t & 31, pr = t >> 5;
#pragma unroll
    for (int p = 0; p < 8; ++p) {
        const int row = p * 8 + pr;
        const __half2 h = __floats2half2_rn(tile[ch2 * 2][row], tile[ch2 * 2 + 1][row]);
        *(__half2*)(dst + (size_t)(pbase + row) * CCH + cbase + ch2 * 2) = h;
    }
}

// ---- main kernel (transposed fp16 layout): block per RoI, lane = channel ----
__global__ __launch_bounds__(256) void fpn_main_t(
    const __half* __restrict__ t2, const __half* __restrict__ t3,
    const __half* __restrict__ t4, const __half* __restrict__ t5,
    const float* __restrict__ rois, const float* __restrict__ im_info,
    float* __restrict__ out, const int* __restrict__ order,
    int H2, int H3, int H4, int H5, int R)
{
    // bijective XCD chunk swizzle
    const int n = blockIdx.x;
    const int q = R / 8, rem = R % 8;
    const int xcd = n % 8, idx = n / 8;
    const int nsw = (xcd < rem ? xcd * (q + 1) : rem * (q + 1) + (xcd - rem) * q) + idx;
    const int r = order ? order[nsw] : nsw;
    const int t = threadIdx.x;   // channel

    const float x1 = rois[r * 5 + 1];
    const float y1 = rois[r * 5 + 2];
    const float x2 = rois[r * 5 + 3];
    const float y2 = rois[r * 5 + 4];

    const int lvl = roi_level(rois, r);
    const __half* feat;
    int H;
    switch (lvl) {
        case 2:  feat = t2; H = H2; break;
        case 3:  feat = t3; H = H3; break;
        case 4:  feat = t4; H = H4; break;
        default: feat = t5; H = H5; break;
    }
    const int W = H;

    // grid coords (exact numpy arithmetic on the index path)
    const float im_h  = im_info[0];
    const float scale = __fdiv_rn((float)H, im_h);
    const float ylo = __fmul_rn(y1, scale), yhi = __fmul_rn(y2, scale);
    const float xlo = __fmul_rn(x1, scale), xhi = __fmul_rn(x2, scale);

    float wy[GRIDG], wx[GRIDG];
    int yoff[GRIDG], dy[GRIDG], xoff[GRIDG], dx[GRIDG];
#pragma unroll
    for (int i = 0; i < GRIDG; ++i) {
        const float tf = __fdiv_rn((float)i, (float)(GRIDG - 1));
        float ty = __fadd_rn(ylo, __fmul_rn(__fsub_rn(yhi, ylo), tf));
        ty = fminf(fmaxf(ty, 0.0f), (float)(H - 1));
        const float y0f = floorf(ty);
        const int   y0  = (int)y0f;
        yoff[i] = y0 * W * CCH;
        dy[i]   = (min(y0 + 1, H - 1) - y0) * W * CCH;
        wy[i]   = __fsub_rn(ty, y0f);

        float tx = __fadd_rn(xlo, __fmul_rn(__fsub_rn(xhi, xlo), tf));
        tx = fminf(fmaxf(tx, 0.0f), (float)(W - 1));
        const float x0f = floorf(tx);
        const int   x0  = (int)x0f;
        xoff[i] = x0 * CCH;
        dx[i]   = (min(x0 + 1, W - 1) - x0) * CCH;
        wx[i]   = __fsub_rn(tx, x0f);
    }

    // f32 staged output in EXACT output layout [c][49] -> drain is a pure copy.
    // Pool-phase writes at stride 49 (odd): bank-bijective, 2-way alias free.
    __shared__ float s_out[CCH * OPP];   // 50176 B

    float rowPrev[GRIDG], rowCur[GRIDG];
#pragma unroll
    for (int gy = 0; gy < GRIDG; ++gy) {
        const __half* base = feat + yoff[gy] + t;
        const int dyg = dy[gy];
        const float wyg = wy[gy];
        const float omy = 1.0f - wyg;
#pragma unroll
        for (int gx = 0; gx < GRIDG; ++gx) {
            const __half* qp = base + xoff[gx];
            const int dxg = dx[gx];
            const float v00 = __half2float(qp[0]);
            const float v01 = __half2float(qp[dxg]);
            const float v10 = __half2float(qp[dyg]);
            const float v11 = __half2float(qp[dyg + dxg]);
            const float wxg = wx[gx];
            const float omx = 1.0f - wxg;
            rowCur[gx] = omy * (omx * v00 + wxg * v01) + wyg * (omx * v10 + wxg * v11);
        }
        if (gy > 0) {
            const int py = gy - 1;
#pragma unroll
            for (int px = 0; px < POOLSZ; ++px) {
                s_out[t * OPP + py * POOLSZ + px] =
                    0.25f * (rowPrev[px] + rowPrev[px + 1] + rowCur[px] + rowCur[px + 1]);
            }
        }
#pragma unroll
        for (int gx = 0; gx < GRIDG; ++gx) rowPrev[gx] = rowCur[gx];
    }

    __syncthreads();
    // pure contiguous drain: 3136 vec4s = 12 full passes + 64-thread tail
    float* obase = out + (size_t)r * (CCH * OPP);
    const float* sp = s_out;
#pragma unroll
    for (int i = 0; i < 12; ++i) {
        const unsigned k4 = (unsigned)(i * 256 + t) * 4u;
        fx4 v;
        v.x = sp[k4 + 0]; v.y = sp[k4 + 1]; v.z = sp[k4 + 2]; v.w = sp[k4 + 3];
        __builtin_nontemporal_store(v, (fx4*)(obase + k4));
    }
    if (t < 64) {
        const unsigned k4 = (unsigned)(12 * 256 + t) * 4u;
        fx4 v;
        v.x = sp[k4 + 0]; v.y = sp[k4 + 1]; v.z = sp[k4 + 2]; v.w = sp[k4 + 3];
        __builtin_nontemporal_store(v, (fx4*)(obase + k4));
    }
}

// ---- fallback (round-3 kernel): only if d_ws can't hold the fp16 copies ----
__global__ __launch_bounds__(256) void fpn_roialign_kernel(
    const float* __restrict__ p2, const float* __restrict__ p3,
    const float* __restrict__ p4, const float* __restrict__ p5,
    const float* __restrict__ rois, const float* __restrict__ im_info,
    float* __restrict__ out, const int* __restrict__ order,
    int H2, int H3, int H4, int H5, int R)
{
    const int n = blockIdx.x;
    const int q = R / 8, rem = R % 8;
    const int xcd = n % 8, idx = n / 8;
    const int nsw = (xcd < rem ? xcd * (q + 1) : rem * (q + 1) + (xcd - rem) * q) + idx;
    const int r = order ? order[nsw] : nsw;

    const float bf = rois[r * 5 + 0];
    const float x1 = rois[r * 5 + 1];
    const float y1 = rois[r * 5 + 2];
    const float x2 = rois[r * 5 + 3];
    const float y2 = rois[r * 5 + 4];

    const int lvl = roi_level(rois, r);
    const float* feat;
    int H;
    switch (lvl) {
        case 2:  feat = p2; H = H2; break;
        case 3:  feat = p3; H = H3; break;
        case 4:  feat = p4; H = H4; break;
        default: feat = p5; H = H5; break;
    }
    const int W = H;
    const int wv  = threadIdx.x >> 6;
    const int lid = threadIdx.x & 63;
    const int gy  = lid >> 3;
    const int gx  = lid & 7;

    const float im_h  = im_info[0];
    const float scale = __fdiv_rn((float)H, im_h);
    const float ylo = __fmul_rn(y1, scale), yhi = __fmul_rn(y2, scale);
    const float xlo = __fmul_rn(x1, scale), xhi = __fmul_rn(x2, scale);
    float ty = __fadd_rn(ylo, __fmul_rn(__fsub_rn(yhi, ylo),
                                        __fdiv_rn((float)gy, (float)(GRIDG - 1))));
    ty = fminf(fmaxf(ty, 0.0f), (float)(H - 1));
    float tx = __fadd_rn(xlo, __fmul_rn(__fsub_rn(xhi, xlo),
                                        __fdiv_rn((float)gx, (float)(GRIDG - 1))));
    tx = fminf(fmaxf(tx, 0.0f), (float)(W - 1));
    const float y0f = floorf(ty), x0f = floorf(tx);
    const int   y0  = (int)y0f,   x0  = (int)x0f;
    const int   y1i = min(y0 + 1, H - 1);
    const int   x1i = min(x0 + 1, W - 1);
    const float wyv = __fsub_rn(ty, y0f);
    const float wxv = __fsub_rn(tx, x0f);
    const float omy = 1.0f - wyv;
    const float omx = 1.0f - wxv;

    const int b = (int)bf;
    const size_t plane = (size_t)H * W;
    const float* fbase = feat + (size_t)(b * CCH + wv * 64) * plane;
    const int o00 = y0  * W + x0;
    const int o01 = y0  * W + x1i;
    const int o10 = y1i * W + x0;
    const int o11 = y1i * W + x1i;

    float* obase = out + (size_t)r * (CCH * OPP) + (size_t)(wv * 64) * OPP;
    const bool wr  = (gy < POOLSZ) && (gx < POOLSZ);
    const int oidx = gy * POOLSZ + gx;

#pragma unroll 4
    for (int k = 0; k < 64; ++k) {
        const float* f = fbase + (size_t)k * plane;
        const float v00 = f[o00];
        const float v01 = f[o01];
        const float v10 = f[o10];
        const float v11 = f[o11];
        const float v = omy * (omx * v00 + wxv * v01) + wyv * (omx * v10 + wxv * v11);
        const float vb  = __shfl_down(v, 8);
        const float vr  = __shfl_down(v, 1);
        const float vbr = __shfl_down(v, 9);
        if (wr) obase[k * OPP + oidx] = 0.25f * (((v + vb) + vr) + vbr);
    }
}

extern "C" void kernel_launch(void* const* d_in, const int* in_sizes, int n_in,
                              void* d_out, int out_size, void* d_ws, size_t ws_size,
                              hipStream_t stream) {
    const float* p2      = (const float*)d_in[0];
    const float* p3      = (const float*)d_in[1];
    const float* p4      = (const float*)d_in[2];
    const float* p5      = (const float*)d_in[3];
    const float* rois    = (const float*)d_in[4];
    const float* im_info = (const float*)d_in[5];
    float* out = (float*)d_out;

    const int R = in_sizes[4] / 5;
    auto dimOf = [](int sz) {
        int hw = sz / CCH;
        return (int)(sqrtf((float)hw) + 0.5f);
    };
    const int H2 = dimOf(in_sizes[0]);
    const int H3 = dimOf(in_sizes[1]);
    const int H4 = dimOf(in_sizes[2]);
    const int H5 = dimOf(in_sizes[3]);
    const size_t HW2 = (size_t)H2 * H2, HW3 = (size_t)H3 * H3;
    const size_t HW4 = (size_t)H4 * H4, HW5 = (size_t)H5 * H5;

    // ws layout: sorted[R] ints | t2 | t3 | t4 | t5 (fp16, 256-byte aligned)
    const size_t sortBytes = (size_t)R * sizeof(int);
    const size_t sortPad   = (sortBytes + 255) & ~(size_t)255;
    const size_t transBytes = (HW2 + HW3 + HW4 + HW5) * CCH * sizeof(__half);
    const bool canSort  = (ws_size >= sortBytes) && (R <= 256 * MAXPER);
    const bool canTrans = ws_size >= sortPad + transBytes;

    if (canTrans) {
        int* sorted = canSort ? (int*)d_ws : nullptr;
        __half* t2 = (__half*)((char*)d_ws + sortPad);
        __half* t3 = t2 + HW2 * CCH;
        __half* t4 = t3 + HW3 * CCH;
        __half* t5 = t4 + HW4 * CCH;
        const int nblkT = (int)((HW2 + HW3 + HW4 + HW5) / 64 * 4);
        const int nblk  = nblkT + (canSort ? 1 : 0);
        prep_kernel<<<nblk, 256, 0, stream>>>(
            p2, p3, p4, p5, t2, t3, t4, t5,
            (int)HW2, (int)HW3, (int)HW4, (int)HW5,
            rois, im_info, R, sorted, nblkT);
        fpn_main_t<<<R, 256, 0, stream>>>(
            t2, t3, t4, t5, rois, im_info, out, sorted, H2, H3, H4, H5, R);
    } else {
        fpn_roialign_kernel<<<R, 256, 0, stream>>>(
            p2, p3, p4, p5, rois, im_info, out, nullptr, H2, H3, H4, H5, R);
    }
}